// Round 10
// baseline (3980.175 us; speedup 1.0000x reference)
//
#include <hip/hip_runtime.h>
#include <math.h>

// Problem constants: B=4096, SORB=64, H=256, NELE=32 (alpha=16), 2 GRU layers
#define BB 4096
#define SS 64
#define HH 256
#define BT 64      // batch rows per WG -> 64 WGs (halves total weight fetch vs BT=32)
#define NT 512     // 8 waves; wave w owns gate tiles nt = tau*16 + 2w + q
#define HPADH 264  // LDS h row stride in halfs (528B: 16B-aligned, 2-way-free banks)

typedef __attribute__((ext_vector_type(8))) _Float16 half8;
typedef __attribute__((ext_vector_type(4))) float    f32x4;

__device__ __forceinline__ float sigmoidf_(float v){ return 1.0f/(1.0f+expf(-v)); }
#define MFMA16(A,B,C) __builtin_amdgcn_mfma_f32_16x16x32_f16((A),(B),(C),0,0,0)

// ---- prologue: pack W into fp16 MFMA-B fragments in d_ws ----
// frag(mat,nt,kt) at halfs (((mat*48+nt)*8+kt)<<9): half[lane*8+j] = W[g][k],
// g = nt*16+(lane&15), k = kt*32+(lane>>4)*8+j.
__global__ void pack_w(const float* __restrict__ Whh0, const float* __restrict__ Wih1,
                       const float* __restrict__ Whh1, _Float16* __restrict__ dst){
    int tid = blockIdx.x*blockDim.x + threadIdx.x;     // [0, 3*48*8*64)
    if (tid >= 3*48*8*64) return;
    int lane = tid & 63;
    int kt   = (tid>>6) & 7;
    int nt   = (tid>>9) % 48;
    int mat  = tid / (48*8*64);
    const float* W = (mat==0) ? Whh0 : (mat==1) ? Wih1 : Whh1;
    int g  = nt*16 + (lane & 15);
    int kb = kt*32 + (lane>>4)*8;
    _Float16* hp = dst + (((mat*48 + nt)*8 + kt) << 9) + lane*8;
    #pragma unroll
    for (int j=0;j<8;++j) hp[j] = (_Float16)W[g*HH + kb + j];
}

// ---- main persistent kernel ----
__global__ __launch_bounds__(NT,2) void rnn_mfma(
    const int*      __restrict__ x,      // (B,S) in {-1,+1}
    const float*    __restrict__ Wih0,   // (768,2)
    const _Float16* __restrict__ wpk_h,  // packed fp16 fragments (d_ws)
    const float*    __restrict__ Wl,     // (2,256)
    const float*    __restrict__ bl,     // (2,)
    float*          __restrict__ out)    // (B,) = real(wf)
{
    __shared__ _Float16 h0h[BT*HPADH];
    __shared__ _Float16 h1h[BT*HPADH];
    __shared__ float    wls[2*HH];
    __shared__ float    red[BT][9][2];
    __shared__ unsigned char bitsS[BT][SS];

    const int t    = threadIdx.x;
    const int L    = t & 63;
    const int w    = t >> 6;       // wave 0..7
    const int lm   = L & 15;
    const int quad = L >> 4;
    const int row0 = blockIdx.x * BT;
    const half8* b0 = (const half8*)wpk_h;            // mat0 (Whh0) frags
    const half8* b1 = (const half8*)wpk_h + 24576;    // mat1 (Wih1)
    const half8* b2 = (const half8*)wpk_h + 49152;    // mat2 (Whh1)

    for (int i=t;i<BT*HPADH;i+=NT){ h0h[i]=(_Float16)0.f; h1h[i]=(_Float16)0.f; }
    for (int i=t;i<2*HH;i+=NT) wls[i]=Wl[i];
    for (int i=t;i<BT*SS;i+=NT){ int b=i>>6,s=i&63; bitsS[b][s]=(x[(row0+b)*SS+s]>0)?1:0; }

    // per-wave fragment indices (half8 units): j -> nt = (j>>1)*16 + 2w + (j&1)
    int fidx[6];
    #pragma unroll
    for (int j=0;j<6;++j) fidx[j] = (((j>>1)*16 + 2*w + (j&1))*8)*64 + L;

    // layer-0 input-gate weights for this lane's 2 owned units (u = 16*(2w+q)+lm)
    float g0w[2][6];
    #pragma unroll
    for (int q=0;q<2;++q){
        int u = 16*(2*w+q) + lm;
        g0w[q][0]=Wih0[u*2+0];        g0w[q][1]=Wih0[u*2+1];
        g0w[q][2]=Wih0[(u+HH)*2+0];   g0w[q][3]=Wih0[(u+HH)*2+1];
        g0w[q][4]=Wih0[(u+2*HH)*2+0]; g0w[q][5]=Wih0[(u+2*HH)*2+1];
    }
    float amp=1.f, ph=0.f, nup=0.f, ndn=0.f;
    const float bl0=bl[0], bl1=bl[1];

    __syncthreads();

    for (int step=0; step<SS; ++step){
        // ---------------- GEMM0: gh0 = h0 @ Whh0^T ----------------
        f32x4 acc0[3][2][4] = {};    // [type][q][mt]
        {
            half8 curB[6], nxtB[6];
            int ktp0 = w & 7;
            #pragma unroll
            for (int j=0;j<6;++j) curB[j] = b0[fidx[j] + ktp0*64];
            for (int kt=0; kt<8; ++kt){
                int ktp = (kt + w) & 7;
                if (kt < 7){
                    int ktn = (kt + 1 + w) & 7;
                    #pragma unroll
                    for (int j=0;j<6;++j) nxtB[j] = b0[fidx[j] + ktn*64];
                }
                half8 A[4];
                #pragma unroll
                for (int mt=0;mt<4;++mt)
                    A[mt] = *(const half8*)(h0h + (mt*16+lm)*HPADH + ktp*32 + quad*8);
                #pragma unroll
                for (int j=0;j<6;++j){
                    #pragma unroll
                    for (int mt=0;mt<4;++mt)
                        acc0[j>>1][j&1][mt] = MFMA16(A[mt], curB[j], acc0[j>>1][j&1][mt]);
                }
                #pragma unroll
                for (int j=0;j<6;++j) curB[j] = nxtB[j];
            }
        }
        __syncthreads();   // all waves done reading h0h

        // ---------------- elementwise 0 (old h0 read back from LDS) ----------------
        #pragma unroll
        for (int q=0;q<2;++q){
            int u = 16*(2*w+q) + lm;
            #pragma unroll
            for (int mt=0;mt<4;++mt){
                #pragma unroll
                for (int reg=0;reg<4;++reg){
                    int m = mt*16 + quad*4 + reg;
                    float gr=0.f,gz=0.f,gn=0.f;
                    if (step>0){
                        int c = bitsS[m][step-1];
                        gr = c?g0w[q][1]:g0w[q][0];
                        gz = c?g0w[q][3]:g0w[q][2];
                        gn = c?g0w[q][5]:g0w[q][4];
                    }
                    float r = sigmoidf_(gr + acc0[0][q][mt][reg]);
                    float z = sigmoidf_(gz + acc0[1][q][mt][reg]);
                    float n = tanhf(gn + r*acc0[2][q][mt][reg]);
                    float hold = (float)h0h[m*HPADH + u];
                    h0h[m*HPADH + u] = (_Float16)((1.f-z)*n + z*hold);
                }
            }
        }
        __syncthreads();   // h0n visible

        // ------- GEMM1 pass A: r,z gates (i+h fused) -------
        f32x4 aR[2][4]={}, aZ[2][4]={};
        {
            half8 cIr[2],cIz[2],cHr[2],cHz[2], nIr[2],nIz[2],nHr[2],nHz[2];
            int ktp0 = w & 7;
            #pragma unroll
            for (int q=0;q<2;++q){
                cIr[q]=b1[fidx[q]+ktp0*64];   cIz[q]=b1[fidx[2+q]+ktp0*64];
                cHr[q]=b2[fidx[q]+ktp0*64];   cHz[q]=b2[fidx[2+q]+ktp0*64];
            }
            for (int kt=0; kt<8; ++kt){
                int ktp = (kt + w) & 7;
                if (kt < 7){
                    int ktn = (kt + 1 + w) & 7;
                    #pragma unroll
                    for (int q=0;q<2;++q){
                        nIr[q]=b1[fidx[q]+ktn*64];   nIz[q]=b1[fidx[2+q]+ktn*64];
                        nHr[q]=b2[fidx[q]+ktn*64];   nHz[q]=b2[fidx[2+q]+ktn*64];
                    }
                }
                half8 A0[4], A1[4];
                #pragma unroll
                for (int mt=0;mt<4;++mt){
                    A0[mt] = *(const half8*)(h0h + (mt*16+lm)*HPADH + ktp*32 + quad*8);
                    A1[mt] = *(const half8*)(h1h + (mt*16+lm)*HPADH + ktp*32 + quad*8);
                }
                #pragma unroll
                for (int q=0;q<2;++q){
                    #pragma unroll
                    for (int mt=0;mt<4;++mt){
                        aR[q][mt] = MFMA16(A0[mt], cIr[q], aR[q][mt]);
                        aR[q][mt] = MFMA16(A1[mt], cHr[q], aR[q][mt]);
                        aZ[q][mt] = MFMA16(A0[mt], cIz[q], aZ[q][mt]);
                        aZ[q][mt] = MFMA16(A1[mt], cHz[q], aZ[q][mt]);
                    }
                }
                #pragma unroll
                for (int q=0;q<2;++q){
                    cIr[q]=nIr[q]; cIz[q]=nIz[q]; cHr[q]=nHr[q]; cHz[q]=nHz[q];
                }
            }
        }
        // ------- GEMM1 pass B: n gate (input / hidden parts separate) -------
        f32x4 aNI[2][4]={}, aNH[2][4]={};
        {
            half8 cIn[2],cHn[2], nIn[2],nHn[2];
            int ktp0 = w & 7;
            #pragma unroll
            for (int q=0;q<2;++q){ cIn[q]=b1[fidx[4+q]+ktp0*64]; cHn[q]=b2[fidx[4+q]+ktp0*64]; }
            for (int kt=0; kt<8; ++kt){
                int ktp = (kt + w) & 7;
                if (kt < 7){
                    int ktn = (kt + 1 + w) & 7;
                    #pragma unroll
                    for (int q=0;q<2;++q){ nIn[q]=b1[fidx[4+q]+ktn*64]; nHn[q]=b2[fidx[4+q]+ktn*64]; }
                }
                half8 A0[4], A1[4];
                #pragma unroll
                for (int mt=0;mt<4;++mt){
                    A0[mt] = *(const half8*)(h0h + (mt*16+lm)*HPADH + ktp*32 + quad*8);
                    A1[mt] = *(const half8*)(h1h + (mt*16+lm)*HPADH + ktp*32 + quad*8);
                }
                #pragma unroll
                for (int q=0;q<2;++q){
                    #pragma unroll
                    for (int mt=0;mt<4;++mt){
                        aNI[q][mt] = MFMA16(A0[mt], cIn[q], aNI[q][mt]);
                        aNH[q][mt] = MFMA16(A1[mt], cHn[q], aNH[q][mt]);
                    }
                }
                #pragma unroll
                for (int q=0;q<2;++q){ cIn[q]=nIn[q]; cHn[q]=nHn[q]; }
            }
        }
        __syncthreads();   // all waves done reading h0h/h1h

        // ---------------- elementwise 1 ----------------
        #pragma unroll
        for (int q=0;q<2;++q){
            int u = 16*(2*w+q) + lm;
            #pragma unroll
            for (int mt=0;mt<4;++mt){
                #pragma unroll
                for (int reg=0;reg<4;++reg){
                    int m = mt*16 + quad*4 + reg;
                    float r = sigmoidf_(aR[q][mt][reg]);
                    float z = sigmoidf_(aZ[q][mt][reg]);
                    float n = tanhf(aNI[q][mt][reg] + r*aNH[q][mt][reg]);
                    float hold = (float)h1h[m*HPADH + u];
                    h1h[m*HPADH + u] = (_Float16)((1.f-z)*n + z*hold);
                }
            }
        }
        __syncthreads();   // h1n visible

        // ---------------- logits partials (512 threads: 64 rows x 8 segs) ----------------
        {
            int b = t>>3, seg = t&7;
            float s0=0.f, s1=0.f;
            #pragma unroll
            for (int j=0;j<32;++j){
                int k = seg*32 + j;
                float hv = (float)h1h[b*HPADH + k];
                s0 += hv*wls[k];
                s1 += hv*wls[HH+k];
            }
            red[b][seg][0]=s0; red[b][seg][1]=s1;
        }
        __syncthreads();

        // ---------------- finalize sampling state (t<64) ----------------
        if (t < BT){
            float l0=bl0, l1=bl1;
            #pragma unroll
            for (int s2=0;s2<8;++s2){ l0+=red[t][s2][0]; l1+=red[t][s2][1]; }

            bool  ev  = (step & 1) == 0;
            float low = -16.f + (float)(step>>1);
            float cnt = ev ? nup : ndn;
            float mocc = (16.f > cnt) ? 1.f : 0.f;
            float mun  = (low  < cnt) ? 1.f : 0.f;

            float mx = fmaxf(l0,l1);
            float e0 = expf(l0-mx), e1 = expf(l1-mx);
            float inv = 1.f/(e0+e1);
            float a0 = sqrtf(e0*inv)*mun;
            float a1 = sqrtf(e1*inv)*mocc;
            float nrm = sqrtf(a0*a0+a1*a1);
            float den = fmaxf(nrm, 1e-12f);
            a0/=den; a1/=den;

            const float PI_F = 3.14159265358979323846f;
            float p0 = PI_F*l0/(1.f+fabsf(l0));
            float p1 = PI_F*l1/(1.f+fabsf(l1));

            int bit = bitsS[t][step];
            amp *= bit ? a1 : a0;
            ph  += bit ? p1 : p0;
            if (ev) nup += (float)bit; else ndn += (float)bit;
        }
        // next writer of red is >=2 barriers away; h protected by B1
    }

    if (t < BT) out[row0 + t] = amp * cosf(ph);
}

extern "C" void kernel_launch(void* const* d_in, const int* in_sizes, int n_in,
                              void* d_out, int out_size, void* d_ws, size_t ws_size,
                              hipStream_t stream) {
    (void)in_sizes; (void)n_in; (void)out_size; (void)ws_size;
    const int*   x    = (const int*)d_in[0];
    const float* Wih0 = (const float*)d_in[1];
    const float* Whh0 = (const float*)d_in[2];
    const float* Wih1 = (const float*)d_in[3];
    const float* Whh1 = (const float*)d_in[4];
    const float* Wl   = (const float*)d_in[5];
    const float* bl   = (const float*)d_in[6];
    float* out = (float*)d_out;
    _Float16* wpk = (_Float16*)d_ws;   // 589824 halfs = 1,179,648 B

    pack_w<<<(3*48*8*64 + 255)/256, 256, 0, stream>>>(Whh0, Wih1, Whh1, wpk);
    rnn_mfma<<<BB/BT, NT, 0, stream>>>(x, Wih0, wpk, Wl, bl, out);
}

// Round 11
// 2677.254 us; speedup vs baseline: 1.4867x; 1.4867x over previous
//
#include <hip/hip_runtime.h>
#include <math.h>

// Problem constants: B=4096, SORB=64, H=256, NELE=32 (alpha=16), 2 GRU layers
#define BB 4096
#define SS 64
#define HH 256
#define BT 32      // batch rows per WG -> 128 WGs
#define NT 512     // 8 waves; wave w owns gate tiles nt = tau*16 + 2w + q
#define HPADH 264  // LDS h row stride in halfs (528B: 16B-aligned, 2-way-free banks)

typedef __attribute__((ext_vector_type(8))) _Float16 half8;
typedef __attribute__((ext_vector_type(4))) float    f32x4;

__device__ __forceinline__ float sigmoidf_(float v){ return 1.0f/(1.0f+expf(-v)); }
#define MFMA16(A,B,C) __builtin_amdgcn_mfma_f32_16x16x32_f16((A),(B),(C),0,0,0)

// ---- prologue: pack W into fp16 MFMA-B fragments in d_ws ----
// frag(mat,nt,kt) at halfs (((mat*48+nt)*8+kt)<<9): half[lane*8+j] = W[g][k],
// g = nt*16+(lane&15), k = kt*32+(lane>>4)*8+j.
__global__ void pack_w(const float* __restrict__ Whh0, const float* __restrict__ Wih1,
                       const float* __restrict__ Whh1, _Float16* __restrict__ dst){
    int tid = blockIdx.x*blockDim.x + threadIdx.x;     // [0, 3*48*8*64)
    if (tid >= 3*48*8*64) return;
    int lane = tid & 63;
    int kt   = (tid>>6) & 7;
    int nt   = (tid>>9) % 48;
    int mat  = tid / (48*8*64);
    const float* W = (mat==0) ? Whh0 : (mat==1) ? Wih1 : Whh1;
    int g  = nt*16 + (lane & 15);
    int kb = kt*32 + (lane>>4)*8;
    _Float16* hp = dst + (((mat*48 + nt)*8 + kt) << 9) + lane*8;
    #pragma unroll
    for (int j=0;j<8;++j) hp[j] = (_Float16)W[g*HH + kb + j];
}

// ---- main persistent kernel ----
// __launch_bounds__(512,1): 2nd arg = min BLOCKS per CU on this toolchain.
// 1 block/CU -> 8 waves/CU (2/SIMD) with a 256-VGPR/thread budget, so the
// 12-fragment register double-buffer actually fits (R7-R10 at (NT,2) got
// VGPR=128 and the compiler serialized the prefetch -> 11.5 B/cyc/CU fetch).
__global__ __launch_bounds__(NT,1) void rnn_mfma(
    const int*      __restrict__ x,      // (B,S) in {-1,+1}
    const float*    __restrict__ Wih0,   // (768,2)
    const _Float16* __restrict__ wpk_h,  // packed fp16 fragments (d_ws)
    const float*    __restrict__ Wl,     // (2,256)
    const float*    __restrict__ bl,     // (2,)
    float*          __restrict__ out)    // (B,) = real(wf)
{
    __shared__ _Float16 h0h[BT*HPADH];
    __shared__ _Float16 h1h[BT*HPADH];
    __shared__ float    wls[2*HH];
    __shared__ float    red[BT][17][2];
    __shared__ unsigned char bitsS[BT][SS];

    const int t    = threadIdx.x;
    const int L    = t & 63;
    const int w    = t >> 6;       // wave 0..7
    const int lm   = L & 15;
    const int quad = L >> 4;
    const int row0 = blockIdx.x * BT;
    const half8* b0 = (const half8*)wpk_h;            // mat0 (Whh0) frags
    const half8* b1 = (const half8*)wpk_h + 24576;    // mat1 (Wih1)
    const half8* b2 = (const half8*)wpk_h + 49152;    // mat2 (Whh1)

    for (int i=t;i<BT*HPADH;i+=NT){ h0h[i]=(_Float16)0.f; h1h[i]=(_Float16)0.f; }
    for (int i=t;i<2*HH;i+=NT) wls[i]=Wl[i];
    for (int i=t;i<BT*SS;i+=NT){ int b=i>>6,s=i&63; bitsS[b][s]=(x[(row0+b)*SS+s]>0)?1:0; }

    // per-wave fragment indices (half8 units): j -> nt = (j>>1)*16 + 2w + (j&1)
    int fidx[6];
    #pragma unroll
    for (int j=0;j<6;++j) fidx[j] = (((j>>1)*16 + 2*w + (j&1))*8)*64 + L;

    // layer-0 input-gate weights for this lane's 2 owned units (u = 16*(2w+q)+lm)
    float g0w[2][6];
    #pragma unroll
    for (int q=0;q<2;++q){
        int u = 16*(2*w+q) + lm;
        g0w[q][0]=Wih0[u*2+0];        g0w[q][1]=Wih0[u*2+1];
        g0w[q][2]=Wih0[(u+HH)*2+0];   g0w[q][3]=Wih0[(u+HH)*2+1];
        g0w[q][4]=Wih0[(u+2*HH)*2+0]; g0w[q][5]=Wih0[(u+2*HH)*2+1];
    }
    float hr0[2][2][4] = {};
    float hr1[2][2][4] = {};
    float amp=1.f, ph=0.f, nup=0.f, ndn=0.f;
    const float bl0=bl[0], bl1=bl[1];

    __syncthreads();

    for (int step=0; step<SS; ++step){
        // ---------------- GEMM0: gh0 = h0 @ Whh0^T ----------------
        f32x4 acc0[3][2][2] = {};    // [type][q][mtile]
        {
            half8 curB[6], nxtB[6];
            #pragma unroll
            for (int j=0;j<6;++j) curB[j] = b0[fidx[j]];          // kt=0
            for (int kt=0; kt<8; ++kt){
                if (kt < 7){
                    #pragma unroll
                    for (int j=0;j<6;++j) nxtB[j] = b0[fidx[j] + (kt+1)*64];
                }
                half8 A[2];
                #pragma unroll
                for (int mt=0;mt<2;++mt)
                    A[mt] = *(const half8*)(h0h + (mt*16+lm)*HPADH + kt*32 + quad*8);
                #pragma unroll
                for (int j=0;j<6;++j){
                    acc0[j>>1][j&1][0] = MFMA16(A[0], curB[j], acc0[j>>1][j&1][0]);
                    acc0[j>>1][j&1][1] = MFMA16(A[1], curB[j], acc0[j>>1][j&1][1]);
                }
                #pragma unroll
                for (int j=0;j<6;++j) curB[j] = nxtB[j];
            }
        }
        __syncthreads();   // all waves done reading h0h

        // ---------------- elementwise 0 ----------------
        #pragma unroll
        for (int q=0;q<2;++q){
            int u = 16*(2*w+q) + lm;
            #pragma unroll
            for (int mt=0;mt<2;++mt){
                #pragma unroll
                for (int reg=0;reg<4;++reg){
                    int m = mt*16 + quad*4 + reg;
                    float gr=0.f,gz=0.f,gn=0.f;
                    if (step>0){
                        int c = bitsS[m][step-1];
                        gr = c?g0w[q][1]:g0w[q][0];
                        gz = c?g0w[q][3]:g0w[q][2];
                        gn = c?g0w[q][5]:g0w[q][4];
                    }
                    float r = sigmoidf_(gr + acc0[0][q][mt][reg]);
                    float z = sigmoidf_(gz + acc0[1][q][mt][reg]);
                    float n = tanhf(gn + r*acc0[2][q][mt][reg]);
                    float hnew = (1.f-z)*n + z*hr0[q][mt][reg];
                    hr0[q][mt][reg] = hnew;
                    h0h[m*HPADH + u] = (_Float16)hnew;
                }
            }
        }
        __syncthreads();   // h0n visible

        // ------- GEMM1: gi1 = h0n@Wih1^T ; gh1 = h1@Whh1^T -------
        f32x4 aR[2][2]={}, aZ[2][2]={}, aNI[2][2]={}, aNH[2][2]={};
        {
            half8 curI[6], curH[6], nxtI[6], nxtH[6];
            #pragma unroll
            for (int j=0;j<6;++j){ curI[j] = b1[fidx[j]]; curH[j] = b2[fidx[j]]; }
            for (int kt=0; kt<8; ++kt){
                if (kt < 7){
                    #pragma unroll
                    for (int j=0;j<6;++j){
                        nxtI[j] = b1[fidx[j] + (kt+1)*64];
                        nxtH[j] = b2[fidx[j] + (kt+1)*64];
                    }
                }
                half8 A0[2], A1[2];
                #pragma unroll
                for (int mt=0;mt<2;++mt){
                    A0[mt] = *(const half8*)(h0h + (mt*16+lm)*HPADH + kt*32 + quad*8);
                    A1[mt] = *(const half8*)(h1h + (mt*16+lm)*HPADH + kt*32 + quad*8);
                }
                #pragma unroll
                for (int j=0;j<6;++j){
                    int tau = j>>1, q = j&1;
                    #pragma unroll
                    for (int mt=0;mt<2;++mt){
                        if (tau==0){
                            aR[q][mt]  = MFMA16(A0[mt], curI[j], aR[q][mt]);
                            aR[q][mt]  = MFMA16(A1[mt], curH[j], aR[q][mt]);
                        } else if (tau==1){
                            aZ[q][mt]  = MFMA16(A0[mt], curI[j], aZ[q][mt]);
                            aZ[q][mt]  = MFMA16(A1[mt], curH[j], aZ[q][mt]);
                        } else {
                            aNI[q][mt] = MFMA16(A0[mt], curI[j], aNI[q][mt]);
                            aNH[q][mt] = MFMA16(A1[mt], curH[j], aNH[q][mt]);
                        }
                    }
                }
                #pragma unroll
                for (int j=0;j<6;++j){ curI[j] = nxtI[j]; curH[j] = nxtH[j]; }
            }
        }
        __syncthreads();   // all waves done reading h0h/h1h

        // ---------------- elementwise 1 ----------------
        #pragma unroll
        for (int q=0;q<2;++q){
            int u = 16*(2*w+q) + lm;
            #pragma unroll
            for (int mt=0;mt<2;++mt){
                #pragma unroll
                for (int reg=0;reg<4;++reg){
                    int m = mt*16 + quad*4 + reg;
                    float r = sigmoidf_(aR[q][mt][reg]);
                    float z = sigmoidf_(aZ[q][mt][reg]);
                    float n = tanhf(aNI[q][mt][reg] + r*aNH[q][mt][reg]);
                    float hnew = (1.f-z)*n + z*hr1[q][mt][reg];
                    hr1[q][mt][reg] = hnew;
                    h1h[m*HPADH + u] = (_Float16)hnew;
                }
            }
        }
        __syncthreads();   // h1n visible

        // ---------------- logits partials (all 512 threads) ----------------
        {
            int b = t>>4, seg = t&15;
            float s0=0.f, s1=0.f;
            #pragma unroll
            for (int j=0;j<16;++j){
                float hv = (float)h1h[b*HPADH + seg*16 + j];
                s0 += hv*wls[seg*16+j];
                s1 += hv*wls[HH+seg*16+j];
            }
            red[b][seg][0]=s0; red[b][seg][1]=s1;
        }
        __syncthreads();

        // ---------------- finalize sampling state (t<32) ----------------
        if (t < BT){
            float l0=bl0, l1=bl1;
            #pragma unroll
            for (int s2=0;s2<16;++s2){ l0+=red[t][s2][0]; l1+=red[t][s2][1]; }

            bool  ev  = (step & 1) == 0;
            float low = -16.f + (float)(step>>1);
            float cnt = ev ? nup : ndn;
            float mocc = (16.f > cnt) ? 1.f : 0.f;
            float mun  = (low  < cnt) ? 1.f : 0.f;

            float mx = fmaxf(l0,l1);
            float e0 = expf(l0-mx), e1 = expf(l1-mx);
            float inv = 1.f/(e0+e1);
            float a0 = sqrtf(e0*inv)*mun;
            float a1 = sqrtf(e1*inv)*mocc;
            float nrm = sqrtf(a0*a0+a1*a1);
            float den = fmaxf(nrm, 1e-12f);
            a0/=den; a1/=den;

            const float PI_F = 3.14159265358979323846f;
            float p0 = PI_F*l0/(1.f+fabsf(l0));
            float p1 = PI_F*l1/(1.f+fabsf(l1));

            int bit = bitsS[t][step];
            amp *= bit ? a1 : a0;
            ph  += bit ? p1 : p0;
            if (ev) nup += (float)bit; else ndn += (float)bit;
        }
        // next writers of red / h are >=2 barriers away
    }

    if (t < BT) out[row0 + t] = amp * cosf(ph);
}

extern "C" void kernel_launch(void* const* d_in, const int* in_sizes, int n_in,
                              void* d_out, int out_size, void* d_ws, size_t ws_size,
                              hipStream_t stream) {
    (void)in_sizes; (void)n_in; (void)out_size; (void)ws_size;
    const int*   x    = (const int*)d_in[0];
    const float* Wih0 = (const float*)d_in[1];
    const float* Whh0 = (const float*)d_in[2];
    const float* Wih1 = (const float*)d_in[3];
    const float* Whh1 = (const float*)d_in[4];
    const float* Wl   = (const float*)d_in[5];
    const float* bl   = (const float*)d_in[6];
    float* out = (float*)d_out;
    _Float16* wpk = (_Float16*)d_ws;   // 589824 halfs = 1,179,648 B

    pack_w<<<(3*48*8*64 + 255)/256, 256, 0, stream>>>(Whh0, Wih1, Whh1, wpk);
    rnn_mfma<<<BB/BT, NT, 0, stream>>>(x, Wih0, wpk, Wl, bl, out);
}